// Round 11
// baseline (1586.249 us; speedup 1.0000x reference)
//
#include <hip/hip_runtime.h>
#include <hip/hip_bf16.h>
#include <stdint.h>

// Problem constants (fixed by the reference)
#define B_   4
#define H_   8
#define SQ_  2048
#define SK_  512
#define DM_  4096
#define DK_  512

typedef __bf16 bf16;
typedef __bf16 bf16x8 __attribute__((ext_vector_type(8)));
typedef float  fx4    __attribute__((ext_vector_type(4)));

// address-space-qualified pointer types for global_load_lds
typedef __attribute__((address_space(1))) void gv_t;   // global
typedef __attribute__((address_space(3))) void lv_t;   // LDS

// ---------------------------------------------------------------------------
// Dtype sniffer (unchanged). flag=1 -> external tensors are fp32.
__global__ void sniff_dtype(const uint32_t* __restrict__ q, int* __restrict__ flag)
{
    const int l = threadIdx.x;  // 64 lanes
    int cnt = 0;
    #pragma unroll
    for (int i = 0; i < 4; ++i) {
        const uint32_t u = q[l * 4 + i];
        const int e = (u >> 7) & 0xFF;
        cnt += (e >= 100 && e <= 135) ? 1 : 0;
    }
    #pragma unroll
    for (int s = 1; s < 64; s <<= 1) cnt += __shfl_xor(cnt, s);
    if (l == 0) *flag = (cnt < 150) ? 1 : 0;
}

// ---------------------------------------------------------------------------
// One-time dtype normalization: fp32 -> bf16 (or bf16 passthrough copy).
__global__ __launch_bounds__(256) void cvt_to_bf16(
    const void* __restrict__ in, bf16* __restrict__ out, const int* __restrict__ flagp)
{
    const size_t i = ((size_t)blockIdx.x * 256 + threadIdx.x) * 8;
    if (*flagp) {
        const float4* p = (const float4*)((const float*)in + i);
        const float4 u0 = p[0], u1 = p[1];
        bf16x8 v;
        v[0] = (bf16)u0.x; v[1] = (bf16)u0.y; v[2] = (bf16)u0.z; v[3] = (bf16)u0.w;
        v[4] = (bf16)u1.x; v[5] = (bf16)u1.y; v[6] = (bf16)u1.z; v[7] = (bf16)u1.w;
        *(bf16x8*)(out + i) = v;
    } else {
        *(bf16x8*)(out + i) = *(const bf16x8*)((const bf16*)in + i);
    }
}

// ---------------------------------------------------------------------------
// Stage two bias vectors contiguously (dtype preserved, per sniffed flag) so
// a z-batched GEMM can index bias per z via bstride. 8192 elems, grid 32x256.
__global__ __launch_bounds__(256) void copy_bias2(
    const void* __restrict__ b1, const void* __restrict__ b2,
    void* __restrict__ dst, const int* __restrict__ flagp)
{
    const int i = blockIdx.x * 256 + threadIdx.x;   // 0..8191
    const void* src = (i < 4096) ? b1 : b2;
    const int j = i & 4095;
    if (*flagp) ((float*)dst)[i] = ((const float*)src)[j];
    else        ((bf16*)dst)[i]  = ((const bf16*)src)[j];
}

// ---------------------------------------------------------------------------
// 128^2-tile GEMM (verified rounds 0-1). Kept for the imf projection only.
__global__ __launch_bounds__(256, 3) void gemm_bt(
    const bf16* __restrict__ A, const bf16* __restrict__ Bt,
    void* __restrict__ Cv, const void* __restrict__ biasv,
    int K, int lda, int ldb, int ldc, float alpha,
    long long sAb, long long sAh, long long sBb, long long sBh,
    long long sCb, long long sCh,
    const int* __restrict__ flagp, int ebits)
{
    __shared__ bf16 sA[128 * 64];
    __shared__ bf16 sB[128 * 64];

    const int fl = ebits ? *flagp : 0;
    const bool bias32 = fl && (ebits & 1);
    const bool c32    = fl && (ebits & 2);

    const int z = blockIdx.z;
    const int bz = z >> 3, hz = z & 7;
    const bf16* Ab = A  + (size_t)bz * sAb + (size_t)hz * sAh;
    const bf16* Bb = Bt + (size_t)bz * sBb + (size_t)hz * sBh;
    const size_t offC = (size_t)bz * sCb + (size_t)hz * sCh;

    const int n0 = blockIdx.x * 128;
    const int m0 = blockIdx.y * 128;

    const int t = threadIdx.x;
    const int w = t >> 6, l = t & 63;
    const int lrow = l >> 3, lcol = l & 7;
    const int wm = (w >> 1) * 64, wn = (w & 1) * 64;
    const int ml = l & 15, quad = l >> 4;

    const bf16* pa[4];
    const bf16* pb[4];
    #pragma unroll
    for (int i = 0; i < 4; ++i) {
        const int c = w * 4 + i;
        const int r = c * 8 + lrow;
        const int jj = lcol ^ (r & 7);
        pa[i] = Ab + (size_t)(m0 + r) * lda + jj * 8;
        pb[i] = Bb + (size_t)(n0 + r) * ldb + jj * 8;
    }

    fx4 acc[4][4];
    const fx4 zero = {0.f, 0.f, 0.f, 0.f};
    #pragma unroll
    for (int i = 0; i < 4; ++i)
        #pragma unroll
        for (int j = 0; j < 4; ++j) acc[i][j] = zero;

    for (int kt = 0; kt < K; kt += 64) {
        #pragma unroll
        for (int i = 0; i < 4; ++i) {
            const int c = w * 4 + i;
            __builtin_amdgcn_global_load_lds((gv_t*)(pa[i] + kt), (lv_t*)(sA + c * 512), 16, 0, 0);
            __builtin_amdgcn_global_load_lds((gv_t*)(pb[i] + kt), (lv_t*)(sB + c * 512), 16, 0, 0);
        }
        __syncthreads();

        #pragma unroll
        for (int kk = 0; kk < 64; kk += 32) {
            bf16x8 af[4], bfr[4];
            const int jbase = (kk >> 3) + quad;
            #pragma unroll
            for (int mi = 0; mi < 4; ++mi) {
                const int r = wm + mi * 16 + ml;
                af[mi] = *(const bf16x8*)&sA[r * 64 + ((jbase ^ (r & 7)) << 3)];
            }
            #pragma unroll
            for (int ni = 0; ni < 4; ++ni) {
                const int r = wn + ni * 16 + ml;
                bfr[ni] = *(const bf16x8*)&sB[r * 64 + ((jbase ^ (r & 7)) << 3)];
            }
            #pragma unroll
            for (int mi = 0; mi < 4; ++mi)
                #pragma unroll
                for (int ni = 0; ni < 4; ++ni)
                    acc[mi][ni] = __builtin_amdgcn_mfma_f32_16x16x32_bf16(
                        af[mi], bfr[ni], acc[mi][ni], 0, 0, 0);
        }
        __syncthreads();
    }

    #pragma unroll
    for (int ni = 0; ni < 4; ++ni) {
        const int cg = n0 + wn + ni * 16 + ml;
        const float bv = biasv ? (bias32 ? ((const float*)biasv)[cg] : (float)((const bf16*)biasv)[cg]) : 0.f;
        #pragma unroll
        for (int mi = 0; mi < 4; ++mi) {
            const int rg = m0 + wm + mi * 16 + quad * 4;
            #pragma unroll
            for (int r = 0; r < 4; ++r) {
                const float val = acc[mi][ni][r] * alpha + bv;
                const size_t idx = offC + (size_t)(rg + r) * ldc + cg;
                if (c32) ((float*)Cv)[idx] = val;
                else     ((bf16*)Cv)[idx] = (bf16)val;
            }
        }
    }
}

// ---------------------------------------------------------------------------
// 256^2 4-phase GEMM, round 11: COUNTED vmcnt (T4), 2 tiles in flight.
// Round-10 measured 47% MfmaUtil with vmcnt(0) drain at every P4; m218's A/B
// (counted-vs-drain0 on this exact structure: +38%@4k) says the drain is the
// residual tax. Change: staging moves to P4, targeting the CURRENT buffer cb
// with tile t+2 (legal: P3's closing barrier proves all waves finished
// reading cb). P4 = {STAGE(t+2->cb); 16 MFMA; vmcnt(8); bar} -- the wait
// retires exactly tile t+1's 8 loads (issued one full tile earlier) while
// t+2's 8 stay in flight across the barrier. vmcnt never reaches 0 in the
// main loop. P1-P3 read phases, barriers, setprio, swizzle: identical to the
// round-10 passing kernel.
#define BARRIER   asm volatile("s_barrier" ::: "memory")
#define LGKM0     asm volatile("s_waitcnt lgkmcnt(0)" ::: "memory")
#define VM0       asm volatile("s_waitcnt vmcnt(0)" ::: "memory")
#define VM8       asm volatile("s_waitcnt vmcnt(8)" ::: "memory")
#define SCHED0    __builtin_amdgcn_sched_barrier(0)

// fragment load: row fr, k-group j=kI*4+quad, XOR slot swizzle (verified 0-conflict)
#define LDS_FRAG(dst, base, fr, kI)                                               \
    dst = *(const bf16x8*)&base[(fr) * 64 + ((((kI) * 4 + quad) ^ ((fr) & 7)) << 3)]

#define READ_A(dst, sX, roff)                                                     \
    _Pragma("unroll")                                                             \
    for (int im_ = 0; im_ < 4; ++im_)                                             \
        _Pragma("unroll")                                                         \
        for (int kI_ = 0; kI_ < 2; ++kI_)                                         \
            LDS_FRAG(dst[im_][kI_], sX, R0 + (roff) + im_ * 16 + ml, kI_);

#define READ_B(dst, sX, coff)                                                     \
    _Pragma("unroll")                                                             \
    for (int in_ = 0; in_ < 2; ++in_)                                             \
        _Pragma("unroll")                                                         \
        for (int kI_ = 0; kI_ < 2; ++kI_)                                         \
            LDS_FRAG(dst[in_][kI_], sX, C0 + (coff) + in_ * 16 + ml, kI_);

#define MFMA_Q(mo, no, afr_, bfr_)                                                \
    __builtin_amdgcn_s_setprio(1);                                                \
    _Pragma("unroll")                                                             \
    for (int kI_ = 0; kI_ < 2; ++kI_)                                             \
        _Pragma("unroll")                                                         \
        for (int im_ = 0; im_ < 4; ++im_)                                         \
            _Pragma("unroll")                                                     \
            for (int in_ = 0; in_ < 2; ++in_)                                     \
                acc[(mo) + im_][(no) + in_] =                                     \
                    __builtin_amdgcn_mfma_f32_16x16x32_bf16(                      \
                        afr_[im_][kI_], bfr_[in_][kI_],                           \
                        acc[(mo) + im_][(no) + in_], 0, 0, 0);                    \
    __builtin_amdgcn_s_setprio(0);

// stage both A-halves of tile ts into buffer sb (4 x 16B loads/thread)
#define STAGE_A(ts, sb)                                                           \
    do {                                                                          \
        _Pragma("unroll")                                                         \
        for (int h_ = 0; h_ < 2; ++h_)                                            \
            _Pragma("unroll")                                                     \
            for (int j_ = 0; j_ < 2; ++j_)                                        \
                __builtin_amdgcn_global_load_lds(                                 \
                    (gv_t*)(pA[h_][j_] + (size_t)(ts) * 64),                      \
                    (lv_t*)(&sm[sb][0][h_ * 8192 + (2 * w + j_) * 512]),          \
                    16, 0, 0);                                                    \
    } while (0)

// stage one B-half h of tile ts into buffer sb (2 x 16B loads/thread)
#define STAGE_B(ts, sb, h)                                                        \
    do {                                                                          \
        _Pragma("unroll")                                                         \
        for (int j_ = 0; j_ < 2; ++j_)                                            \
            __builtin_amdgcn_global_load_lds(                                     \
                (gv_t*)(pB[h][j_] + (size_t)(ts) * 64),                           \
                (lv_t*)(&sm[sb][1][(h) * 8192 + (2 * w + j_) * 512]),             \
                16, 0, 0);                                                        \
    } while (0)

// One K-tile: consume buf cb; at P4 stage tile ts into the SAME buf cb
// (all reads of cb completed by P3's closing barrier), counted wait.
#define TILE_ITER(cb, ts, dostage)                                                \
    do {                                                                          \
        const bf16* sA_ = &sm[cb][0][0];                                          \
        const bf16* sB_ = &sm[cb][1][0];                                          \
        /* P1 */                                                                  \
        READ_A(afr, sA_, 0);                                                      \
        READ_B(b0r, sB_, 0);                                                      \
        BARRIER; LGKM0; SCHED0;                                                   \
        MFMA_Q(0, 0, afr, b0r);                                                   \
        BARRIER;                                                                  \
        /* P2 */                                                                  \
        READ_B(b1r, sB_, 32);                                                     \
        BARRIER; LGKM0; SCHED0;                                                   \
        MFMA_Q(0, 2, afr, b1r);                                                   \
        BARRIER;                                                                  \
        /* P3 */                                                                  \
        READ_A(afr, sA_, 64);                                                     \
        BARRIER; LGKM0; SCHED0;                                                   \
        MFMA_Q(4, 2, afr, b1r);                                                   \
        BARRIER;  /* <- all waves done reading cb entirely */                     \
        /* P4: stage t+2 into cb under the MFMAs; counted wait for t+1 */         \
        if (dostage) { STAGE_A(ts, cb); STAGE_B(ts, cb, 0); STAGE_B(ts, cb, 1); } \
        MFMA_Q(4, 0, afr, b0r);                                                   \
        if (dostage) { VM8; } else { VM0; }                                       \
        BARRIER;                                                                  \
    } while (0)

__global__ __launch_bounds__(512, 2) void gemm256(
    const bf16* __restrict__ A, const bf16* __restrict__ Bt,
    void* __restrict__ Cv, const void* __restrict__ biasv,
    int K, int lda, int ldb, int ldc, float alpha,
    long long sAb, long long sAh, long long sBb, long long sBh,
    long long sCb, long long sCh,
    const int* __restrict__ flagp, int ebits, int bstride)
{
    __shared__ bf16 sm[2][2][256 * 64];   // [buf][A/B][tile] = 128 KiB

    const int fl = ebits ? *flagp : 0;
    const bool bias32 = fl && (ebits & 1);
    const bool c32    = fl && (ebits & 2);

    // ---- XCD-bijective block swizzle (all grids here are %8==0) ----
    const int gX = gridDim.x, gY = gridDim.y;
    int idx = (blockIdx.z * gY + blockIdx.y) * gX + blockIdx.x;
    const int nwg = gX * gY * gridDim.z;
    if ((nwg & 7) == 0) idx = (idx & 7) * (nwg >> 3) + (idx >> 3);
    const int bx = idx % gX;
    const int tmpi = idx / gX;
    const int by = tmpi % gY;
    const int z  = tmpi / gY;

    const int bz = z >> 3, hz = z & 7;
    const bf16* Ab = A  + (size_t)bz * sAb + (size_t)hz * sAh;
    const bf16* Bb = Bt + (size_t)bz * sBb + (size_t)hz * sBh;
    const size_t offC = (size_t)bz * sCb + (size_t)hz * sCh;

    const int n0 = bx * 256;
    const int m0 = by * 256;

    const int t  = threadIdx.x;
    const int w  = t >> 6, l = t & 63;
    const int lrow = l >> 3, lcol = l & 7;          // staging decomposition
    const int wr = w >> 2, wc = w & 3;              // wave grid 2x4
    const int R0 = wr * 128, C0 = wc * 64;          // per-wave C sub-tile
    const int ml = l & 15, quad = l >> 4;           // MFMA fragment lanes

    // staging pointers: half h (128 rows), load j -> chunk 2w+j of that half
    const bf16* pA[2][2];
    const bf16* pB[2][2];
    #pragma unroll
    for (int h = 0; h < 2; ++h)
        #pragma unroll
        for (int j = 0; j < 2; ++j) {
            const int r = h * 128 + (2 * w + j) * 8 + lrow;
            const int jj = lcol ^ (r & 7);
            pA[h][j] = Ab + (size_t)(m0 + r) * lda + jj * 8;
            pB[h][j] = Bb + (size_t)(n0 + r) * ldb + jj * 8;
        }

    fx4 acc[8][4];
    const fx4 zero = {0.f, 0.f, 0.f, 0.f};
    #pragma unroll
    for (int i = 0; i < 8; ++i)
        #pragma unroll
        for (int j = 0; j < 4; ++j) acc[i][j] = zero;

    bf16x8 afr[4][2], b0r[2][2], b1r[2][2];

    const int nt  = K >> 6;    // K-tiles of 64 (8 or 64 here -> always even)
    const int nit = nt >> 1;   // iterations of 2 K-tiles

    // ---- prologue: stage tiles 0,1; counted wait (tile 1 stays in flight) ----
    STAGE_A(0, 0);
    STAGE_B(0, 0, 0);
    STAGE_B(0, 0, 1);
    STAGE_A(1, 1);
    STAGE_B(1, 1, 0);
    STAGE_B(1, 1, 1);
    VM8;        // tile 0's 8 landed; tile 1's 8 remain in flight
    BARRIER;

    for (int it = 0; it < nit; ++it) {
        const bool more = (it + 1 < nit);
        // consume tile 2it (buf0); stage tile 2it+2 into buf0 at P4
        TILE_ITER(0, 2 * it + 2, more);
        // consume tile 2it+1 (buf1); stage tile 2it+3 into buf1 at P4
        TILE_ITER(1, 2 * it + 3, more);
    }

    // ---- epilogue: C/D layout col=lane&15, row=(lane>>4)*4+reg ----
    #pragma unroll
    for (int ni = 0; ni < 4; ++ni) {
        const int cg = n0 + C0 + ni * 16 + ml;
        const int bix = hz * bstride + cg;
        const float bv = biasv ? (bias32 ? ((const float*)biasv)[bix] : (float)((const bf16*)biasv)[bix]) : 0.f;
        #pragma unroll
        for (int mi = 0; mi < 8; ++mi) {
            const int rg = m0 + R0 + mi * 16 + quad * 4;
            #pragma unroll
            for (int r = 0; r < 4; ++r) {
                const float val = acc[mi][ni][r] * alpha + bv;
                const size_t idx = offC + (size_t)(rg + r) * ldc + cg;
                if (c32) ((float*)Cv)[idx] = val;
                else     ((bf16*)Cv)[idx] = (bf16)val;
            }
        }
    }
}

// In-place row softmax, rows of exactly 512 bf16. One wave per row (8 elems/lane).
__global__ __launch_bounds__(256) void softmax512(bf16* __restrict__ buf)
{
    const int row = blockIdx.x * 4 + (threadIdx.x >> 6);
    const int l = threadIdx.x & 63;
    bf16* p = buf + (size_t)row * 512 + l * 8;
    bf16x8 v = *(const bf16x8*)p;
    float f[8];
    float mx = -1e30f;
    #pragma unroll
    for (int j = 0; j < 8; ++j) {
        f[j] = (float)v[j];
        if (!(fabsf(f[j]) < 1e30f)) f[j] = -1e9f;   // NaN/Inf guard
        mx = fmaxf(mx, f[j]);
    }
    #pragma unroll
    for (int s = 1; s < 64; s <<= 1) mx = fmaxf(mx, __shfl_xor(mx, s));
    float sum = 0.f;
    #pragma unroll
    for (int j = 0; j < 8; ++j) { f[j] = __expf(f[j] - mx); sum += f[j]; }
    #pragma unroll
    for (int s = 1; s < 64; s <<= 1) sum += __shfl_xor(sum, s);
    const float inv = 1.f / sum;
    #pragma unroll
    for (int j = 0; j < 8; ++j) v[j] = (bf16)(f[j] * inv);
    *(bf16x8*)p = v;
}

// out[z][d][s] = in[b][s][h*512+d], z = b*8+h. 32x32 tiles via LDS. (internal bf16)
__global__ __launch_bounds__(256) void transpose_heads(
    const bf16* __restrict__ in, bf16* __restrict__ out)
{
    __shared__ bf16 tile[32][33];
    const int z = blockIdx.z, b = z >> 3, h = z & 7;
    const int s0 = blockIdx.x * 32, d0 = blockIdx.y * 32;
    const int tx = threadIdx.x, ty = threadIdx.y;   // 32 x 8
    #pragma unroll
    for (int j = 0; j < 4; ++j) {
        const int s = s0 + ty + j * 8;
        tile[ty + j * 8][tx] = in[(size_t)b * SK_ * DM_ + (size_t)s * DM_ + h * DK_ + d0 + tx];
    }
    __syncthreads();
    #pragma unroll
    for (int j = 0; j < 4; ++j) {
        const int d = d0 + ty + j * 8;
        out[(size_t)z * DK_ * SK_ + (size_t)d * SK_ + s0 + tx] = tile[tx][ty + j * 8];
    }
}

extern "C" void kernel_launch(void* const* d_in, const int* in_sizes, int n_in,
                              void* d_out, int out_size, void* d_ws, size_t ws_size,
                              hipStream_t stream)
{
    const void* query = d_in[0];
    const void* key   = d_in[1];
    const void* value = d_in[2];
    const void* imf   = d_in[3];
    const void* W0 = d_in[4];  const void* b0 = d_in[5];
    const void* W1 = d_in[6];  const void* b1 = d_in[7];
    const void* W2 = d_in[8];  const void* b2 = d_in[9];
    const void* W3 = d_in[10]; const void* b3 = d_in[11];

    // ---- workspace (bf16 elems; >=58.7M proven). Liveness-audited offsets:
    bf16* ws    = (bf16*)d_ws;
    int*  flagp = (int*)d_ws;
    bf16* wS1   = ws + 8;                    // 16.8M: W0 -> W1 -> (vT,imfT) -> W3final
    bf16* wS2   = ws + 16777224;             // 16.8M: W2 -> W3 -> s1/xcat start
    bf16* vT    = ws + 8;                    //  8.4M (W slots dead after KV GEMM)
    bf16* imfT  = ws + 8388616;              //  8.4M
    bf16* w3s   = ws + 16777224;             // 16.8M (dead after imf GEMM)
    bf16* imfp  = ws + 33554440;             //  8.4M (dead after transpose)
    bf16* s1    = ws + 16777224;             // 33.5M (overlays dead w3s+imfp; ends 50.3M)
    bf16* xcat  = ws + 16777224;             // 33.5M (overlays dead s1)
    bf16* w3f   = ws + 8;                    // 16.8M (after vT/imfT die)
    bf16* wbias = ws + 50331656;             // 16K: staged b1|b2 (dtype follows flag)

    // ---- d_out (67.1M bf16 elems), multi-duty until final GEMM fills it ----
    bf16* obase = (bf16*)d_out;
    bf16* qproj = obase;                     // 33.5M (dead after scores GEMM)
    bf16* qbf   = obase + 33554432;          // 33.5M (dead after Q proj)
    bf16* kin   = obase + 33554432;          //  8.4M (k/v contiguous inputs)
    bf16* vin   = obase + 41943040;          //  8.4M
    bf16* iin   = obase + 33554432;          //  8.4M (reuses dead kin)
    bf16* kproj = obase + 50331648;          //  8.4M (kproj/vproj contiguous, sCh=8.4M)
    bf16* vproj = obase + 58720256;          //  8.4M (dead after transpose)
    bf16* s2    = obase + 33554432;          // 33.5M (after iin/vin/kproj/vproj die)

    const float inv_sqrt_dk = 0.04419417382415922f;  // 1/sqrt(512)

    // 0: decide external dtype (fp32 vs bf16) from query's bit patterns
    sniff_dtype<<<1, 64, 0, stream>>>((const uint32_t*)query, flagp);

    // ---- Q path: convert, project (16x32 = 512 WGs = 2 full rounds) ----
    cvt_to_bf16<<<16384, 256, 0, stream>>>(query, qbf, flagp);
    cvt_to_bf16<<<8192, 256, 0, stream>>>(W0, wS1, flagp);
    gemm256<<<dim3(16, 32, 1), 512, 0, stream>>>(qbf, wS1, qproj, b0,
        4096, 4096, 4096, 4096, 1.f, 0,0,0,0,0,0, flagp, 1, 0);

    // ---- K+V batched projection: z=2, grid (16,8,2) = 256 WGs = 1 WG/CU ----
    cvt_to_bf16<<<4096, 256, 0, stream>>>(key, kin, flagp);
    cvt_to_bf16<<<4096, 256, 0, stream>>>(value, vin, flagp);
    cvt_to_bf16<<<8192, 256, 0, stream>>>(W1, wS1, flagp);
    cvt_to_bf16<<<8192, 256, 0, stream>>>(W2, wS2, flagp);
    copy_bias2<<<32, 256, 0, stream>>>(b1, b2, wbias, flagp);
    gemm256<<<dim3(16, 8, 2), 512, 0, stream>>>(kin, wS1, kproj, wbias,
        4096, 4096, 4096, 4096, 1.f,
        0LL, 8388608LL, 0LL, 16777216LL, 0LL, 8388608LL,
        flagp, 1, 4096);

    // ---- imf projection (gemm_bt: 512 WGs fills better than 128-WG 256^2) ----
    cvt_to_bf16<<<4096, 256, 0, stream>>>(imf, iin, flagp);
    cvt_to_bf16<<<8192, 256, 0, stream>>>(W3, w3s, flagp);
    gemm_bt<<<dim3(32, 16, 1), 256, 0, stream>>>(iin, w3s, imfp, b3,
        4096, 4096, 4096, 4096, 1.f, 0,0,0,0,0,0, flagp, 1);

    // ---- per-head transposes so the @imf and @v einsums become A·B^T ----
    transpose_heads<<<dim3(16, 16, 32), dim3(32, 8), 0, stream>>>(vproj, vT);
    transpose_heads<<<dim3(16, 16, 32), dim3(32, 8), 0, stream>>>(imfp, imfT);

    // ---- scores = q·k^T / sqrt(dk)  (2x8x32 = 512 WGs) ----
    gemm256<<<dim3(2, 8, 32), 512, 0, stream>>>(qproj, kproj, s1, nullptr,
        512, 4096, 4096, 512, inv_sqrt_dk,
        (long long)SQ_*DM_, (long long)DK_, (long long)SK_*DM_, (long long)DK_,
        (long long)H_*SQ_*SK_, (long long)SQ_*SK_, flagp, 0, 0);
    softmax512<<<dim3(16384), 256, 0, stream>>>(s1);
    // ---- s2 = p @ imf_h ----
    gemm256<<<dim3(2, 8, 32), 512, 0, stream>>>(s1, imfT, s2, nullptr,
        512, 512, 512, 512, 1.f,
        (long long)H_*SQ_*SK_, (long long)SQ_*SK_, (long long)H_*DK_*SK_, (long long)DK_*SK_,
        (long long)H_*SQ_*SK_, (long long)SQ_*SK_, flagp, 0, 0);
    softmax512<<<dim3(16384), 256, 0, stream>>>(s2);
    // ---- x = im_attn @ v_h -> concat-head layout (xcat overlays dead s1) ----
    gemm256<<<dim3(2, 8, 32), 512, 0, stream>>>(s2, vT, xcat, nullptr,
        512, 512, 512, 4096, 1.f,
        (long long)H_*SQ_*SK_, (long long)SQ_*SK_, (long long)H_*DK_*SK_, (long long)DK_*SK_,
        (long long)SQ_*DM_, (long long)DK_, flagp, 0, 0);
    // ---- out = xcat @ W3^T + b3 (re-convert W3 into dead vT/imfT region) ----
    cvt_to_bf16<<<8192, 256, 0, stream>>>(W3, w3f, flagp);
    gemm256<<<dim3(16, 32, 1), 512, 0, stream>>>(xcat, w3f, d_out, b3,
        4096, 4096, 4096, 4096, 1.f, 0,0,0,0,0,0, flagp, 3, 0);
}

// Round 12
// 1493.093 us; speedup vs baseline: 1.0624x; 1.0624x over previous
//
#include <hip/hip_runtime.h>
#include <hip/hip_bf16.h>
#include <stdint.h>

// Problem constants (fixed by the reference)
#define B_   4
#define H_   8
#define SQ_  2048
#define SK_  512
#define DM_  4096
#define DK_  512

typedef __bf16 bf16;
typedef __bf16 bf16x8 __attribute__((ext_vector_type(8)));
typedef float  fx4    __attribute__((ext_vector_type(4)));

// address-space-qualified pointer types for global_load_lds
typedef __attribute__((address_space(1))) void gv_t;   // global
typedef __attribute__((address_space(3))) void lv_t;   // LDS

// ---------------------------------------------------------------------------
// Dtype sniffer (unchanged). flag=1 -> external tensors are fp32.
__global__ void sniff_dtype(const uint32_t* __restrict__ q, int* __restrict__ flag)
{
    const int l = threadIdx.x;  // 64 lanes
    int cnt = 0;
    #pragma unroll
    for (int i = 0; i < 4; ++i) {
        const uint32_t u = q[l * 4 + i];
        const int e = (u >> 7) & 0xFF;
        cnt += (e >= 100 && e <= 135) ? 1 : 0;
    }
    #pragma unroll
    for (int s = 1; s < 64; s <<= 1) cnt += __shfl_xor(cnt, s);
    if (l == 0) *flag = (cnt < 150) ? 1 : 0;
}

// ---------------------------------------------------------------------------
// One-time dtype normalization: fp32 -> bf16 (or bf16 passthrough copy).
__global__ __launch_bounds__(256) void cvt_to_bf16(
    const void* __restrict__ in, bf16* __restrict__ out, const int* __restrict__ flagp)
{
    const size_t i = ((size_t)blockIdx.x * 256 + threadIdx.x) * 8;
    if (*flagp) {
        const float4* p = (const float4*)((const float*)in + i);
        const float4 u0 = p[0], u1 = p[1];
        bf16x8 v;
        v[0] = (bf16)u0.x; v[1] = (bf16)u0.y; v[2] = (bf16)u0.z; v[3] = (bf16)u0.w;
        v[4] = (bf16)u1.x; v[5] = (bf16)u1.y; v[6] = (bf16)u1.z; v[7] = (bf16)u1.w;
        *(bf16x8*)(out + i) = v;
    } else {
        *(bf16x8*)(out + i) = *(const bf16x8*)((const bf16*)in + i);
    }
}

// ---------------------------------------------------------------------------
// Stage two bias vectors contiguously (dtype preserved, per sniffed flag) so
// a z-batched GEMM can index bias per z via bstride. 8192 elems, grid 32x256.
__global__ __launch_bounds__(256) void copy_bias2(
    const void* __restrict__ b1, const void* __restrict__ b2,
    void* __restrict__ dst, const int* __restrict__ flagp)
{
    const int i = blockIdx.x * 256 + threadIdx.x;   // 0..8191
    const void* src = (i < 4096) ? b1 : b2;
    const int j = i & 4095;
    if (*flagp) ((float*)dst)[i] = ((const float*)src)[j];
    else        ((bf16*)dst)[i]  = ((const bf16*)src)[j];
}

// ---------------------------------------------------------------------------
// 128^2-tile GEMM (verified rounds 0-1). Kept for the imf projection only.
__global__ __launch_bounds__(256, 3) void gemm_bt(
    const bf16* __restrict__ A, const bf16* __restrict__ Bt,
    void* __restrict__ Cv, const void* __restrict__ biasv,
    int K, int lda, int ldb, int ldc, float alpha,
    long long sAb, long long sAh, long long sBb, long long sBh,
    long long sCb, long long sCh,
    const int* __restrict__ flagp, int ebits)
{
    __shared__ bf16 sA[128 * 64];
    __shared__ bf16 sB[128 * 64];

    const int fl = ebits ? *flagp : 0;
    const bool bias32 = fl && (ebits & 1);
    const bool c32    = fl && (ebits & 2);

    const int z = blockIdx.z;
    const int bz = z >> 3, hz = z & 7;
    const bf16* Ab = A  + (size_t)bz * sAb + (size_t)hz * sAh;
    const bf16* Bb = Bt + (size_t)bz * sBb + (size_t)hz * sBh;
    const size_t offC = (size_t)bz * sCb + (size_t)hz * sCh;

    const int n0 = blockIdx.x * 128;
    const int m0 = blockIdx.y * 128;

    const int t = threadIdx.x;
    const int w = t >> 6, l = t & 63;
    const int lrow = l >> 3, lcol = l & 7;
    const int wm = (w >> 1) * 64, wn = (w & 1) * 64;
    const int ml = l & 15, quad = l >> 4;

    const bf16* pa[4];
    const bf16* pb[4];
    #pragma unroll
    for (int i = 0; i < 4; ++i) {
        const int c = w * 4 + i;
        const int r = c * 8 + lrow;
        const int jj = lcol ^ (r & 7);
        pa[i] = Ab + (size_t)(m0 + r) * lda + jj * 8;
        pb[i] = Bb + (size_t)(n0 + r) * ldb + jj * 8;
    }

    fx4 acc[4][4];
    const fx4 zero = {0.f, 0.f, 0.f, 0.f};
    #pragma unroll
    for (int i = 0; i < 4; ++i)
        #pragma unroll
        for (int j = 0; j < 4; ++j) acc[i][j] = zero;

    for (int kt = 0; kt < K; kt += 64) {
        #pragma unroll
        for (int i = 0; i < 4; ++i) {
            const int c = w * 4 + i;
            __builtin_amdgcn_global_load_lds((gv_t*)(pa[i] + kt), (lv_t*)(sA + c * 512), 16, 0, 0);
            __builtin_amdgcn_global_load_lds((gv_t*)(pb[i] + kt), (lv_t*)(sB + c * 512), 16, 0, 0);
        }
        __syncthreads();

        #pragma unroll
        for (int kk = 0; kk < 64; kk += 32) {
            bf16x8 af[4], bfr[4];
            const int jbase = (kk >> 3) + quad;
            #pragma unroll
            for (int mi = 0; mi < 4; ++mi) {
                const int r = wm + mi * 16 + ml;
                af[mi] = *(const bf16x8*)&sA[r * 64 + ((jbase ^ (r & 7)) << 3)];
            }
            #pragma unroll
            for (int ni = 0; ni < 4; ++ni) {
                const int r = wn + ni * 16 + ml;
                bfr[ni] = *(const bf16x8*)&sB[r * 64 + ((jbase ^ (r & 7)) << 3)];
            }
            #pragma unroll
            for (int mi = 0; mi < 4; ++mi)
                #pragma unroll
                for (int ni = 0; ni < 4; ++ni)
                    acc[mi][ni] = __builtin_amdgcn_mfma_f32_16x16x32_bf16(
                        af[mi], bfr[ni], acc[mi][ni], 0, 0, 0);
        }
        __syncthreads();
    }

    #pragma unroll
    for (int ni = 0; ni < 4; ++ni) {
        const int cg = n0 + wn + ni * 16 + ml;
        const float bv = biasv ? (bias32 ? ((const float*)biasv)[cg] : (float)((const bf16*)biasv)[cg]) : 0.f;
        #pragma unroll
        for (int mi = 0; mi < 4; ++mi) {
            const int rg = m0 + wm + mi * 16 + quad * 4;
            #pragma unroll
            for (int r = 0; r < 4; ++r) {
                const float val = acc[mi][ni][r] * alpha + bv;
                const size_t idx = offC + (size_t)(rg + r) * ldc + cg;
                if (c32) ((float*)Cv)[idx] = val;
                else     ((bf16*)Cv)[idx] = (bf16)val;
            }
        }
    }
}

// ---------------------------------------------------------------------------
// 256^2 4-phase GEMM, round 12: REVERT to round-10's verified per-phase
// staging interleave (45-47% MfmaUtil, 267us) with ONE micro-change: staging
// shifted one phase earlier (P1: A-halves + Bh0 = 6 loads; P2: Bh1 = 2;
// P3: none). Round-11's A/B proved bundled-staging+counted-wait loses to
// spread-staging+drain (315 vs 267us): the per-phase interleave is the
// active ingredient. The remaining drain tax was the P3-issued loads (~600cyc
// < 900cyc HBM latency before P4's vmcnt(0)); with last issue at P2 the drain
// has >=2 phases (~1200cyc) of cover and becomes ~free. All other structure
// byte-identical to round 10.
#define BARRIER   asm volatile("s_barrier" ::: "memory")
#define LGKM0     asm volatile("s_waitcnt lgkmcnt(0)" ::: "memory")
#define VM0       asm volatile("s_waitcnt vmcnt(0)" ::: "memory")
#define SCHED0    __builtin_amdgcn_sched_barrier(0)

// fragment load: row fr, k-group j=kI*4+quad, XOR slot swizzle (verified 0-conflict)
#define LDS_FRAG(dst, base, fr, kI)                                               \
    dst = *(const bf16x8*)&base[(fr) * 64 + ((((kI) * 4 + quad) ^ ((fr) & 7)) << 3)]

#define READ_A(dst, sX, roff)                                                     \
    _Pragma("unroll")                                                             \
    for (int im_ = 0; im_ < 4; ++im_)                                             \
        _Pragma("unroll")                                                         \
        for (int kI_ = 0; kI_ < 2; ++kI_)                                         \
            LDS_FRAG(dst[im_][kI_], sX, R0 + (roff) + im_ * 16 + ml, kI_);

#define READ_B(dst, sX, coff)                                                     \
    _Pragma("unroll")                                                             \
    for (int in_ = 0; in_ < 2; ++in_)                                             \
        _Pragma("unroll")                                                         \
        for (int kI_ = 0; kI_ < 2; ++kI_)                                         \
            LDS_FRAG(dst[in_][kI_], sX, C0 + (coff) + in_ * 16 + ml, kI_);

#define MFMA_Q(mo, no, afr_, bfr_)                                                \
    __builtin_amdgcn_s_setprio(1);                                                \
    _Pragma("unroll")                                                             \
    for (int kI_ = 0; kI_ < 2; ++kI_)                                             \
        _Pragma("unroll")                                                         \
        for (int im_ = 0; im_ < 4; ++im_)                                         \
            _Pragma("unroll")                                                     \
            for (int in_ = 0; in_ < 2; ++in_)                                     \
                acc[(mo) + im_][(no) + in_] =                                     \
                    __builtin_amdgcn_mfma_f32_16x16x32_bf16(                      \
                        afr_[im_][kI_], bfr_[in_][kI_],                           \
                        acc[(mo) + im_][(no) + in_], 0, 0, 0);                    \
    __builtin_amdgcn_s_setprio(0);

// stage both A-halves of tile ts into buffer sb (4 x 16B loads/thread)
#define STAGE_A(ts, sb)                                                           \
    do {                                                                          \
        _Pragma("unroll")                                                         \
        for (int h_ = 0; h_ < 2; ++h_)                                            \
            _Pragma("unroll")                                                     \
            for (int j_ = 0; j_ < 2; ++j_)                                        \
                __builtin_amdgcn_global_load_lds(                                 \
                    (gv_t*)(pA[h_][j_] + (size_t)(ts) * 64),                      \
                    (lv_t*)(&sm[sb][0][h_ * 8192 + (2 * w + j_) * 512]),          \
                    16, 0, 0);                                                    \
    } while (0)

// stage one B-half h of tile ts into buffer sb (2 x 16B loads/thread)
#define STAGE_B(ts, sb, h)                                                        \
    do {                                                                          \
        _Pragma("unroll")                                                         \
        for (int j_ = 0; j_ < 2; ++j_)                                            \
            __builtin_amdgcn_global_load_lds(                                     \
                (gv_t*)(pB[h][j_] + (size_t)(ts) * 64),                           \
                (lv_t*)(&sm[sb][1][(h) * 8192 + (2 * w + j_) * 512]),             \
                16, 0, 0);                                                        \
    } while (0)

#define HALF_ITER(cb, ts, sb, dostage)                                            \
    do {                                                                          \
        const bf16* sA_ = &sm[cb][0][0];                                          \
        const bf16* sB_ = &sm[cb][1][0];                                          \
        /* P1: reads + stage A-halves AND Bh0 (6 loads) */                        \
        READ_A(afr, sA_, 0);                                                      \
        READ_B(b0r, sB_, 0);                                                      \
        if (dostage) { STAGE_A(ts, sb); STAGE_B(ts, sb, 0); }                     \
        BARRIER; LGKM0; SCHED0;                                                   \
        MFMA_Q(0, 0, afr, b0r);                                                   \
        BARRIER;                                                                  \
        /* P2: reads + stage Bh1 (last 2 loads; >=2 phases before the drain) */   \
        READ_B(b1r, sB_, 32);                                                     \
        if (dostage) { STAGE_B(ts, sb, 1); }                                      \
        BARRIER; LGKM0; SCHED0;                                                   \
        MFMA_Q(0, 2, afr, b1r);                                                   \
        BARRIER;                                                                  \
        /* P3: reads only */                                                      \
        READ_A(afr, sA_, 64);                                                     \
        BARRIER; LGKM0; SCHED0;                                                   \
        MFMA_Q(4, 2, afr, b1r);                                                   \
        BARRIER;                                                                  \
        /* P4: pure MFMA; drain staged DMA (now latency-covered); handoff */      \
        MFMA_Q(4, 0, afr, b0r);                                                   \
        VM0;                                                                      \
        BARRIER;                                                                  \
    } while (0)

__global__ __launch_bounds__(512, 2) void gemm256(
    const bf16* __restrict__ A, const bf16* __restrict__ Bt,
    void* __restrict__ Cv, const void* __restrict__ biasv,
    int K, int lda, int ldb, int ldc, float alpha,
    long long sAb, long long sAh, long long sBb, long long sBh,
    long long sCb, long long sCh,
    const int* __restrict__ flagp, int ebits, int bstride)
{
    __shared__ bf16 sm[2][2][256 * 64];   // [buf][A/B][tile] = 128 KiB

    const int fl = ebits ? *flagp : 0;
    const bool bias32 = fl && (ebits & 1);
    const bool c32    = fl && (ebits & 2);

    // ---- XCD-bijective block swizzle (all grids here are %8==0) ----
    const int gX = gridDim.x, gY = gridDim.y;
    int idx = (blockIdx.z * gY + blockIdx.y) * gX + blockIdx.x;
    const int nwg = gX * gY * gridDim.z;
    if ((nwg & 7) == 0) idx = (idx & 7) * (nwg >> 3) + (idx >> 3);
    const int bx = idx % gX;
    const int tmpi = idx / gX;
    const int by = tmpi % gY;
    const int z  = tmpi / gY;

    const int bz = z >> 3, hz = z & 7;
    const bf16* Ab = A  + (size_t)bz * sAb + (size_t)hz * sAh;
    const bf16* Bb = Bt + (size_t)bz * sBb + (size_t)hz * sBh;
    const size_t offC = (size_t)bz * sCb + (size_t)hz * sCh;

    const int n0 = bx * 256;
    const int m0 = by * 256;

    const int t  = threadIdx.x;
    const int w  = t >> 6, l = t & 63;
    const int lrow = l >> 3, lcol = l & 7;          // staging decomposition
    const int wr = w >> 2, wc = w & 3;              // wave grid 2x4
    const int R0 = wr * 128, C0 = wc * 64;          // per-wave C sub-tile
    const int ml = l & 15, quad = l >> 4;           // MFMA fragment lanes

    // staging pointers: half h (128 rows), load j -> chunk 2w+j of that half
    const bf16* pA[2][2];
    const bf16* pB[2][2];
    #pragma unroll
    for (int h = 0; h < 2; ++h)
        #pragma unroll
        for (int j = 0; j < 2; ++j) {
            const int r = h * 128 + (2 * w + j) * 8 + lrow;
            const int jj = lcol ^ (r & 7);
            pA[h][j] = Ab + (size_t)(m0 + r) * lda + jj * 8;
            pB[h][j] = Bb + (size_t)(n0 + r) * ldb + jj * 8;
        }

    fx4 acc[8][4];
    const fx4 zero = {0.f, 0.f, 0.f, 0.f};
    #pragma unroll
    for (int i = 0; i < 8; ++i)
        #pragma unroll
        for (int j = 0; j < 4; ++j) acc[i][j] = zero;

    bf16x8 afr[4][2], b0r[2][2], b1r[2][2];

    const int nt  = K >> 6;    // K-tiles of 64 (8 or 64 here -> always even)
    const int nit = nt >> 1;   // iterations of 2 K-tiles

    // ---- prologue: stage tile 0 -> buf0 fully; drain; sync ----
    STAGE_A(0, 0);
    STAGE_B(0, 0, 0);
    STAGE_B(0, 0, 1);
    VM0;
    BARRIER;

    for (int it = 0; it < nit; ++it) {
        // consume tile 2it (buf0); stage tile 2it+1 -> buf1 (consumed next half)
        HALF_ITER(0, 2 * it + 1, 1, true);
        // consume tile 2it+1 (buf1); stage tile 2it+2 -> buf0 (next iteration)
        HALF_ITER(1, 2 * it + 2, 0, (it + 1 < nit));
    }

    // ---- epilogue: C/D layout col=lane&15, row=(lane>>4)*4+reg ----
    #pragma unroll
    for (int ni = 0; ni < 4; ++ni) {
        const int cg = n0 + C0 + ni * 16 + ml;
        const int bix = hz * bstride + cg;
        const float bv = biasv ? (bias32 ? ((const float*)biasv)[bix] : (float)((const bf16*)biasv)[bix]) : 0.f;
        #pragma unroll
        for (int mi = 0; mi < 8; ++mi) {
            const int rg = m0 + R0 + mi * 16 + quad * 4;
            #pragma unroll
            for (int r = 0; r < 4; ++r) {
                const float val = acc[mi][ni][r] * alpha + bv;
                const size_t idx = offC + (size_t)(rg + r) * ldc + cg;
                if (c32) ((float*)Cv)[idx] = val;
                else     ((bf16*)Cv)[idx] = (bf16)val;
            }
        }
    }
}

// In-place row softmax, rows of exactly 512 bf16. One wave per row (8 elems/lane).
__global__ __launch_bounds__(256) void softmax512(bf16* __restrict__ buf)
{
    const int row = blockIdx.x * 4 + (threadIdx.x >> 6);
    const int l = threadIdx.x & 63;
    bf16* p = buf + (size_t)row * 512 + l * 8;
    bf16x8 v = *(const bf16x8*)p;
    float f[8];
    float mx = -1e30f;
    #pragma unroll
    for (int j = 0; j < 8; ++j) {
        f[j] = (float)v[j];
        if (!(fabsf(f[j]) < 1e30f)) f[j] = -1e9f;   // NaN/Inf guard
        mx = fmaxf(mx, f[j]);
    }
    #pragma unroll
    for (int s = 1; s < 64; s <<= 1) mx = fmaxf(mx, __shfl_xor(mx, s));
    float sum = 0.f;
    #pragma unroll
    for (int j = 0; j < 8; ++j) { f[j] = __expf(f[j] - mx); sum += f[j]; }
    #pragma unroll
    for (int s = 1; s < 64; s <<= 1) sum += __shfl_xor(sum, s);
    const float inv = 1.f / sum;
    #pragma unroll
    for (int j = 0; j < 8; ++j) v[j] = (bf16)(f[j] * inv);
    *(bf16x8*)p = v;
}

// out[z][d][s] = in[b][s][h*512+d], z = b*8+h. 32x32 tiles via LDS. (internal bf16)
__global__ __launch_bounds__(256) void transpose_heads(
    const bf16* __restrict__ in, bf16* __restrict__ out)
{
    __shared__ bf16 tile[32][33];
    const int z = blockIdx.z, b = z >> 3, h = z & 7;
    const int s0 = blockIdx.x * 32, d0 = blockIdx.y * 32;
    const int tx = threadIdx.x, ty = threadIdx.y;   // 32 x 8
    #pragma unroll
    for (int j = 0; j < 4; ++j) {
        const int s = s0 + ty + j * 8;
        tile[ty + j * 8][tx] = in[(size_t)b * SK_ * DM_ + (size_t)s * DM_ + h * DK_ + d0 + tx];
    }
    __syncthreads();
    #pragma unroll
    for (int j = 0; j < 4; ++j) {
        const int d = d0 + ty + j * 8;
        out[(size_t)z * DK_ * SK_ + (size_t)d * SK_ + s0 + tx] = tile[tx][ty + j * 8];
    }
}

extern "C" void kernel_launch(void* const* d_in, const int* in_sizes, int n_in,
                              void* d_out, int out_size, void* d_ws, size_t ws_size,
                              hipStream_t stream)
{
    const void* query = d_in[0];
    const void* key   = d_in[1];
    const void* value = d_in[2];
    const void* imf   = d_in[3];
    const void* W0 = d_in[4];  const void* b0 = d_in[5];
    const void* W1 = d_in[6];  const void* b1 = d_in[7];
    const void* W2 = d_in[8];  const void* b2 = d_in[9];
    const void* W3 = d_in[10]; const void* b3 = d_in[11];

    // ---- workspace (bf16 elems; >=58.7M proven). Liveness-audited offsets:
    bf16* ws    = (bf16*)d_ws;
    int*  flagp = (int*)d_ws;
    bf16* wS1   = ws + 8;                    // 16.8M: W0 -> W1 -> (vT,imfT) -> W3final
    bf16* wS2   = ws + 16777224;             // 16.8M: W2 -> W3 -> s1/xcat start
    bf16* vT    = ws + 8;                    //  8.4M (W slots dead after KV GEMM)
    bf16* imfT  = ws + 8388616;              //  8.4M
    bf16* w3s   = ws + 16777224;             // 16.8M (dead after imf GEMM)
    bf16* imfp  = ws + 33554440;             //  8.4M (dead after transpose)
    bf16* s1    = ws + 16777224;             // 33.5M (overlays dead w3s+imfp; ends 50.3M)
    bf16* xcat  = ws + 16777224;             // 33.5M (overlays dead s1)
    bf16* w3f   = ws + 8;                    // 16.8M (after vT/imfT die)
    bf16* wbias = ws + 50331656;             // 16K: staged b1|b2 (dtype follows flag)

    // ---- d_out (67.1M bf16 elems), multi-duty until final GEMM fills it ----
    bf16* obase = (bf16*)d_out;
    bf16* qproj = obase;                     // 33.5M (dead after scores GEMM)
    bf16* qbf   = obase + 33554432;          // 33.5M (dead after Q proj)
    bf16* kin   = obase + 33554432;          //  8.4M (k/v contiguous inputs)
    bf16* vin   = obase + 41943040;          //  8.4M
    bf16* iin   = obase + 33554432;          //  8.4M (reuses dead kin)
    bf16* kproj = obase + 50331648;          //  8.4M (kproj/vproj contiguous, sCh=8.4M)
    bf16* vproj = obase + 58720256;          //  8.4M (dead after transpose)
    bf16* s2    = obase + 33554432;          // 33.5M (after iin/vin/kproj/vproj die)

    const float inv_sqrt_dk = 0.04419417382415922f;  // 1/sqrt(512)

    // 0: decide external dtype (fp32 vs bf16) from query's bit patterns
    sniff_dtype<<<1, 64, 0, stream>>>((const uint32_t*)query, flagp);

    // ---- Q path: convert, project (16x32 = 512 WGs = 2 full rounds) ----
    cvt_to_bf16<<<16384, 256, 0, stream>>>(query, qbf, flagp);
    cvt_to_bf16<<<8192, 256, 0, stream>>>(W0, wS1, flagp);
    gemm256<<<dim3(16, 32, 1), 512, 0, stream>>>(qbf, wS1, qproj, b0,
        4096, 4096, 4096, 4096, 1.f, 0,0,0,0,0,0, flagp, 1, 0);

    // ---- K+V batched projection: z=2, grid (16,8,2) = 256 WGs = 1 WG/CU ----
    cvt_to_bf16<<<4096, 256, 0, stream>>>(key, kin, flagp);
    cvt_to_bf16<<<4096, 256, 0, stream>>>(value, vin, flagp);
    cvt_to_bf16<<<8192, 256, 0, stream>>>(W1, wS1, flagp);
    cvt_to_bf16<<<8192, 256, 0, stream>>>(W2, wS2, flagp);
    copy_bias2<<<32, 256, 0, stream>>>(b1, b2, wbias, flagp);
    gemm256<<<dim3(16, 8, 2), 512, 0, stream>>>(kin, wS1, kproj, wbias,
        4096, 4096, 4096, 4096, 1.f,
        0LL, 8388608LL, 0LL, 16777216LL, 0LL, 8388608LL,
        flagp, 1, 4096);

    // ---- imf projection (gemm_bt: 512 WGs fills better than 128-WG 256^2) ----
    cvt_to_bf16<<<4096, 256, 0, stream>>>(imf, iin, flagp);
    cvt_to_bf16<<<8192, 256, 0, stream>>>(W3, w3s, flagp);
    gemm_bt<<<dim3(32, 16, 1), 256, 0, stream>>>(iin, w3s, imfp, b3,
        4096, 4096, 4096, 4096, 1.f, 0,0,0,0,0,0, flagp, 1);

    // ---- per-head transposes so the @imf and @v einsums become A·B^T ----
    transpose_heads<<<dim3(16, 16, 32), dim3(32, 8), 0, stream>>>(vproj, vT);
    transpose_heads<<<dim3(16, 16, 32), dim3(32, 8), 0, stream>>>(imfp, imfT);

    // ---- scores = q·k^T / sqrt(dk)  (2x8x32 = 512 WGs) ----
    gemm256<<<dim3(2, 8, 32), 512, 0, stream>>>(qproj, kproj, s1, nullptr,
        512, 4096, 4096, 512, inv_sqrt_dk,
        (long long)SQ_*DM_, (long long)DK_, (long long)SK_*DM_, (long long)DK_,
        (long long)H_*SQ_*SK_, (long long)SQ_*SK_, flagp, 0, 0);
    softmax512<<<dim3(16384), 256, 0, stream>>>(s1);
    // ---- s2 = p @ imf_h ----
    gemm256<<<dim3(2, 8, 32), 512, 0, stream>>>(s1, imfT, s2, nullptr,
        512, 512, 512, 512, 1.f,
        (long long)H_*SQ_*SK_, (long long)SQ_*SK_, (long long)H_*DK_*SK_, (long long)DK_*SK_,
        (long long)H_*SQ_*SK_, (long long)SQ_*SK_, flagp, 0, 0);
    softmax512<<<dim3(16384), 256, 0, stream>>>(s2);
    // ---- x = im_attn @ v_h -> concat-head layout (xcat overlays dead s1) ----
    gemm256<<<dim3(2, 8, 32), 512, 0, stream>>>(s2, vT, xcat, nullptr,
        512, 512, 512, 4096, 1.f,
        (long long)H_*SQ_*SK_, (long long)SQ_*SK_, (long long)H_*DK_*SK_, (long long)DK_*SK_,
        (long long)SQ_*DM_, (long long)DK_, flagp, 0, 0);
    // ---- out = xcat @ W3^T + b3 (re-convert W3 into dead vT/imfT region) ----
    cvt_to_bf16<<<8192, 256, 0, stream>>>(W3, w3f, flagp);
    gemm256<<<dim3(16, 32, 1), 512, 0, stream>>>(xcat, w3f, d_out, b3,
        4096, 4096, 4096, 4096, 1.f, 0,0,0,0,0,0, flagp, 3, 0);
}

// Round 13
// 1462.726 us; speedup vs baseline: 1.0844x; 1.0208x over previous
//
#include <hip/hip_runtime.h>
#include <hip/hip_bf16.h>
#include <stdint.h>

// Problem constants (fixed by the reference)
#define B_   4
#define H_   8
#define SQ_  2048
#define SK_  512
#define DM_  4096
#define DK_  512

typedef __bf16 bf16;
typedef __bf16 bf16x8 __attribute__((ext_vector_type(8)));
typedef float  fx4    __attribute__((ext_vector_type(4)));

// address-space-qualified pointer types for global_load_lds
typedef __attribute__((address_space(1))) void gv_t;   // global
typedef __attribute__((address_space(3))) void lv_t;   // LDS

// ---------------------------------------------------------------------------
// Dtype sniffer (unchanged). flag=1 -> external tensors are fp32.
__global__ void sniff_dtype(const uint32_t* __restrict__ q, int* __restrict__ flag)
{
    const int l = threadIdx.x;  // 64 lanes
    int cnt = 0;
    #pragma unroll
    for (int i = 0; i < 4; ++i) {
        const uint32_t u = q[l * 4 + i];
        const int e = (u >> 7) & 0xFF;
        cnt += (e >= 100 && e <= 135) ? 1 : 0;
    }
    #pragma unroll
    for (int s = 1; s < 64; s <<= 1) cnt += __shfl_xor(cnt, s);
    if (l == 0) *flag = (cnt < 150) ? 1 : 0;
}

// ---------------------------------------------------------------------------
// One-time dtype normalization: fp32 -> bf16 (or bf16 passthrough copy).
__global__ __launch_bounds__(256) void cvt_to_bf16(
    const void* __restrict__ in, bf16* __restrict__ out, const int* __restrict__ flagp)
{
    const size_t i = ((size_t)blockIdx.x * 256 + threadIdx.x) * 8;
    if (*flagp) {
        const float4* p = (const float4*)((const float*)in + i);
        const float4 u0 = p[0], u1 = p[1];
        bf16x8 v;
        v[0] = (bf16)u0.x; v[1] = (bf16)u0.y; v[2] = (bf16)u0.z; v[3] = (bf16)u0.w;
        v[4] = (bf16)u1.x; v[5] = (bf16)u1.y; v[6] = (bf16)u1.z; v[7] = (bf16)u1.w;
        *(bf16x8*)(out + i) = v;
    } else {
        *(bf16x8*)(out + i) = *(const bf16x8*)((const bf16*)in + i);
    }
}

// ---------------------------------------------------------------------------
// Two-tensor variant: blocks [0,n1) convert in1->out1, the rest in2->out2.
// Same per-block body as cvt_to_bf16; saves one launch + its gap.
__global__ __launch_bounds__(256) void cvt2_to_bf16(
    const void* __restrict__ in1, bf16* __restrict__ out1,
    const void* __restrict__ in2, bf16* __restrict__ out2,
    int n1, const int* __restrict__ flagp)
{
    const int second = (int)blockIdx.x >= n1;
    const void* in = second ? in2 : in1;
    bf16* out = second ? out2 : out1;
    const int bid = second ? ((int)blockIdx.x - n1) : (int)blockIdx.x;
    const size_t i = ((size_t)bid * 256 + threadIdx.x) * 8;
    if (*flagp) {
        const float4* p = (const float4*)((const float*)in + i);
        const float4 u0 = p[0], u1 = p[1];
        bf16x8 v;
        v[0] = (bf16)u0.x; v[1] = (bf16)u0.y; v[2] = (bf16)u0.z; v[3] = (bf16)u0.w;
        v[4] = (bf16)u1.x; v[5] = (bf16)u1.y; v[6] = (bf16)u1.z; v[7] = (bf16)u1.w;
        *(bf16x8*)(out + i) = v;
    } else {
        *(bf16x8*)(out + i) = *(const bf16x8*)((const bf16*)in + i);
    }
}

// ---------------------------------------------------------------------------
// Stage two bias vectors contiguously (dtype preserved, per sniffed flag) so
// a z-batched GEMM can index bias per z via bstride. 8192 elems, grid 32x256.
__global__ __launch_bounds__(256) void copy_bias2(
    const void* __restrict__ b1, const void* __restrict__ b2,
    void* __restrict__ dst, const int* __restrict__ flagp)
{
    const int i = blockIdx.x * 256 + threadIdx.x;   // 0..8191
    const void* src = (i < 4096) ? b1 : b2;
    const int j = i & 4095;
    if (*flagp) ((float*)dst)[i] = ((const float*)src)[j];
    else        ((bf16*)dst)[i]  = ((const bf16*)src)[j];
}

// ---------------------------------------------------------------------------
// 128^2-tile GEMM (verified rounds 0-1). Kept for the imf projection only.
__global__ __launch_bounds__(256, 3) void gemm_bt(
    const bf16* __restrict__ A, const bf16* __restrict__ Bt,
    void* __restrict__ Cv, const void* __restrict__ biasv,
    int K, int lda, int ldb, int ldc, float alpha,
    long long sAb, long long sAh, long long sBb, long long sBh,
    long long sCb, long long sCh,
    const int* __restrict__ flagp, int ebits)
{
    __shared__ bf16 sA[128 * 64];
    __shared__ bf16 sB[128 * 64];

    const int fl = ebits ? *flagp : 0;
    const bool bias32 = fl && (ebits & 1);
    const bool c32    = fl && (ebits & 2);

    const int z = blockIdx.z;
    const int bz = z >> 3, hz = z & 7;
    const bf16* Ab = A  + (size_t)bz * sAb + (size_t)hz * sAh;
    const bf16* Bb = Bt + (size_t)bz * sBb + (size_t)hz * sBh;
    const size_t offC = (size_t)bz * sCb + (size_t)hz * sCh;

    const int n0 = blockIdx.x * 128;
    const int m0 = blockIdx.y * 128;

    const int t = threadIdx.x;
    const int w = t >> 6, l = t & 63;
    const int lrow = l >> 3, lcol = l & 7;
    const int wm = (w >> 1) * 64, wn = (w & 1) * 64;
    const int ml = l & 15, quad = l >> 4;

    const bf16* pa[4];
    const bf16* pb[4];
    #pragma unroll
    for (int i = 0; i < 4; ++i) {
        const int c = w * 4 + i;
        const int r = c * 8 + lrow;
        const int jj = lcol ^ (r & 7);
        pa[i] = Ab + (size_t)(m0 + r) * lda + jj * 8;
        pb[i] = Bb + (size_t)(n0 + r) * ldb + jj * 8;
    }

    fx4 acc[4][4];
    const fx4 zero = {0.f, 0.f, 0.f, 0.f};
    #pragma unroll
    for (int i = 0; i < 4; ++i)
        #pragma unroll
        for (int j = 0; j < 4; ++j) acc[i][j] = zero;

    for (int kt = 0; kt < K; kt += 64) {
        #pragma unroll
        for (int i = 0; i < 4; ++i) {
            const int c = w * 4 + i;
            __builtin_amdgcn_global_load_lds((gv_t*)(pa[i] + kt), (lv_t*)(sA + c * 512), 16, 0, 0);
            __builtin_amdgcn_global_load_lds((gv_t*)(pb[i] + kt), (lv_t*)(sB + c * 512), 16, 0, 0);
        }
        __syncthreads();

        #pragma unroll
        for (int kk = 0; kk < 64; kk += 32) {
            bf16x8 af[4], bfr[4];
            const int jbase = (kk >> 3) + quad;
            #pragma unroll
            for (int mi = 0; mi < 4; ++mi) {
                const int r = wm + mi * 16 + ml;
                af[mi] = *(const bf16x8*)&sA[r * 64 + ((jbase ^ (r & 7)) << 3)];
            }
            #pragma unroll
            for (int ni = 0; ni < 4; ++ni) {
                const int r = wn + ni * 16 + ml;
                bfr[ni] = *(const bf16x8*)&sB[r * 64 + ((jbase ^ (r & 7)) << 3)];
            }
            #pragma unroll
            for (int mi = 0; mi < 4; ++mi)
                #pragma unroll
                for (int ni = 0; ni < 4; ++ni)
                    acc[mi][ni] = __builtin_amdgcn_mfma_f32_16x16x32_bf16(
                        af[mi], bfr[ni], acc[mi][ni], 0, 0, 0);
        }
        __syncthreads();
    }

    #pragma unroll
    for (int ni = 0; ni < 4; ++ni) {
        const int cg = n0 + wn + ni * 16 + ml;
        const float bv = biasv ? (bias32 ? ((const float*)biasv)[cg] : (float)((const bf16*)biasv)[cg]) : 0.f;
        #pragma unroll
        for (int mi = 0; mi < 4; ++mi) {
            const int rg = m0 + wm + mi * 16 + quad * 4;
            #pragma unroll
            for (int r = 0; r < 4; ++r) {
                const float val = acc[mi][ni][r] * alpha + bv;
                const size_t idx = offC + (size_t)(rg + r) * ldc + cg;
                if (c32) ((float*)Cv)[idx] = val;
                else     ((bf16*)Cv)[idx] = (bf16)val;
            }
        }
    }
}

// ---------------------------------------------------------------------------
// 256^2 4-phase GEMM — EXACT round-10 schedule (verified best: 267us, 45-47%
// MfmaUtil, e2e 1454). Staging spread 4/2/2 across P1/P2/P3 into the OTHER
// buffer sb; vmcnt(0) drain at P4. The round-11/12 A/Bs mapped this as the
// local optimum (bundled+counted=315, 6/2/0+drain=283). Do not perturb.
#define BARRIER   asm volatile("s_barrier" ::: "memory")
#define LGKM0     asm volatile("s_waitcnt lgkmcnt(0)" ::: "memory")
#define VM0       asm volatile("s_waitcnt vmcnt(0)" ::: "memory")
#define SCHED0    __builtin_amdgcn_sched_barrier(0)

// fragment load: row fr, k-group j=kI*4+quad, XOR slot swizzle (verified 0-conflict)
#define LDS_FRAG(dst, base, fr, kI)                                               \
    dst = *(const bf16x8*)&base[(fr) * 64 + ((((kI) * 4 + quad) ^ ((fr) & 7)) << 3)]

#define READ_A(dst, sX, roff)                                                     \
    _Pragma("unroll")                                                             \
    for (int im_ = 0; im_ < 4; ++im_)                                             \
        _Pragma("unroll")                                                         \
        for (int kI_ = 0; kI_ < 2; ++kI_)                                         \
            LDS_FRAG(dst[im_][kI_], sX, R0 + (roff) + im_ * 16 + ml, kI_);

#define READ_B(dst, sX, coff)                                                     \
    _Pragma("unroll")                                                             \
    for (int in_ = 0; in_ < 2; ++in_)                                             \
        _Pragma("unroll")                                                         \
        for (int kI_ = 0; kI_ < 2; ++kI_)                                         \
            LDS_FRAG(dst[in_][kI_], sX, C0 + (coff) + in_ * 16 + ml, kI_);

#define MFMA_Q(mo, no, afr_, bfr_)                                                \
    __builtin_amdgcn_s_setprio(1);                                                \
    _Pragma("unroll")                                                             \
    for (int kI_ = 0; kI_ < 2; ++kI_)                                             \
        _Pragma("unroll")                                                         \
        for (int im_ = 0; im_ < 4; ++im_)                                         \
            _Pragma("unroll")                                                     \
            for (int in_ = 0; in_ < 2; ++in_)                                     \
                acc[(mo) + im_][(no) + in_] =                                     \
                    __builtin_amdgcn_mfma_f32_16x16x32_bf16(                      \
                        afr_[im_][kI_], bfr_[in_][kI_],                           \
                        acc[(mo) + im_][(no) + in_], 0, 0, 0);                    \
    __builtin_amdgcn_s_setprio(0);

// stage both A-halves of tile ts into buffer sb (4 x 16B loads/thread)
#define STAGE_A(ts, sb)                                                           \
    do {                                                                          \
        _Pragma("unroll")                                                         \
        for (int h_ = 0; h_ < 2; ++h_)                                            \
            _Pragma("unroll")                                                     \
            for (int j_ = 0; j_ < 2; ++j_)                                        \
                __builtin_amdgcn_global_load_lds(                                 \
                    (gv_t*)(pA[h_][j_] + (size_t)(ts) * 64),                      \
                    (lv_t*)(&sm[sb][0][h_ * 8192 + (2 * w + j_) * 512]),          \
                    16, 0, 0);                                                    \
    } while (0)

// stage one B-half h of tile ts into buffer sb (2 x 16B loads/thread)
#define STAGE_B(ts, sb, h)                                                        \
    do {                                                                          \
        _Pragma("unroll")                                                         \
        for (int j_ = 0; j_ < 2; ++j_)                                            \
            __builtin_amdgcn_global_load_lds(                                     \
                (gv_t*)(pB[h][j_] + (size_t)(ts) * 64),                           \
                (lv_t*)(&sm[sb][1][(h) * 8192 + (2 * w + j_) * 512]),             \
                16, 0, 0);                                                        \
    } while (0)

#define HALF_ITER(cb, ts, sb, dostage)                                            \
    do {                                                                          \
        const bf16* sA_ = &sm[cb][0][0];                                          \
        const bf16* sB_ = &sm[cb][1][0];                                          \
        /* P1: reads + stage A-halves (4 loads) */                                \
        READ_A(afr, sA_, 0);                                                      \
        READ_B(b0r, sB_, 0);                                                      \
        if (dostage) { STAGE_A(ts, sb); }                                         \
        BARRIER; LGKM0; SCHED0;                                                   \
        MFMA_Q(0, 0, afr, b0r);                                                   \
        BARRIER;                                                                  \
        /* P2: reads + stage Bh0 (2 loads) */                                     \
        READ_B(b1r, sB_, 32);                                                     \
        if (dostage) { STAGE_B(ts, sb, 0); }                                      \
        BARRIER; LGKM0; SCHED0;                                                   \
        MFMA_Q(0, 2, afr, b1r);                                                   \
        BARRIER;                                                                  \
        /* P3: reads + stage Bh1 (2 loads) */                                     \
        READ_A(afr, sA_, 64);                                                     \
        if (dostage) { STAGE_B(ts, sb, 1); }                                      \
        BARRIER; LGKM0; SCHED0;                                                   \
        MFMA_Q(4, 2, afr, b1r);                                                   \
        BARRIER;                                                                  \
        /* P4: pure MFMA; drain staged DMA; buffer handoff */                     \
        MFMA_Q(4, 0, afr, b0r);                                                   \
        VM0;                                                                      \
        BARRIER;                                                                  \
    } while (0)

__global__ __launch_bounds__(512, 2) void gemm256(
    const bf16* __restrict__ A, const bf16* __restrict__ Bt,
    void* __restrict__ Cv, const void* __restrict__ biasv,
    int K, int lda, int ldb, int ldc, float alpha,
    long long sAb, long long sAh, long long sBb, long long sBh,
    long long sCb, long long sCh,
    const int* __restrict__ flagp, int ebits, int bstride)
{
    __shared__ bf16 sm[2][2][256 * 64];   // [buf][A/B][tile] = 128 KiB

    const int fl = ebits ? *flagp : 0;
    const bool bias32 = fl && (ebits & 1);
    const bool c32    = fl && (ebits & 2);

    // ---- XCD-bijective block swizzle (all grids here are %8==0) ----
    const int gX = gridDim.x, gY = gridDim.y;
    int idx = (blockIdx.z * gY + blockIdx.y) * gX + blockIdx.x;
    const int nwg = gX * gY * gridDim.z;
    if ((nwg & 7) == 0) idx = (idx & 7) * (nwg >> 3) + (idx >> 3);
    const int bx = idx % gX;
    const int tmpi = idx / gX;
    const int by = tmpi % gY;
    const int z  = tmpi / gY;

    const int bz = z >> 3, hz = z & 7;
    const bf16* Ab = A  + (size_t)bz * sAb + (size_t)hz * sAh;
    const bf16* Bb = Bt + (size_t)bz * sBb + (size_t)hz * sBh;
    const size_t offC = (size_t)bz * sCb + (size_t)hz * sCh;

    const int n0 = bx * 256;
    const int m0 = by * 256;

    const int t  = threadIdx.x;
    const int w  = t >> 6, l = t & 63;
    const int lrow = l >> 3, lcol = l & 7;          // staging decomposition
    const int wr = w >> 2, wc = w & 3;              // wave grid 2x4
    const int R0 = wr * 128, C0 = wc * 64;          // per-wave C sub-tile
    const int ml = l & 15, quad = l >> 4;           // MFMA fragment lanes

    // staging pointers: half h (128 rows), load j -> chunk 2w+j of that half
    const bf16* pA[2][2];
    const bf16* pB[2][2];
    #pragma unroll
    for (int h = 0; h < 2; ++h)
        #pragma unroll
        for (int j = 0; j < 2; ++j) {
            const int r = h * 128 + (2 * w + j) * 8 + lrow;
            const int jj = lcol ^ (r & 7);
            pA[h][j] = Ab + (size_t)(m0 + r) * lda + jj * 8;
            pB[h][j] = Bb + (size_t)(n0 + r) * ldb + jj * 8;
        }

    fx4 acc[8][4];
    const fx4 zero = {0.f, 0.f, 0.f, 0.f};
    #pragma unroll
    for (int i = 0; i < 8; ++i)
        #pragma unroll
        for (int j = 0; j < 4; ++j) acc[i][j] = zero;

    bf16x8 afr[4][2], b0r[2][2], b1r[2][2];

    const int nt  = K >> 6;    // K-tiles of 64 (8 or 64 here -> always even)
    const int nit = nt >> 1;   // iterations of 2 K-tiles

    // ---- prologue: stage tile 0 -> buf0 fully; drain; sync ----
    STAGE_A(0, 0);
    STAGE_B(0, 0, 0);
    STAGE_B(0, 0, 1);
    VM0;
    BARRIER;

    for (int it = 0; it < nit; ++it) {
        // consume tile 2it (buf0); stage tile 2it+1 -> buf1 (consumed next half)
        HALF_ITER(0, 2 * it + 1, 1, true);
        // consume tile 2it+1 (buf1); stage tile 2it+2 -> buf0 (next iteration)
        HALF_ITER(1, 2 * it + 2, 0, (it + 1 < nit));
    }

    // ---- epilogue: C/D layout col=lane&15, row=(lane>>4)*4+reg ----
    #pragma unroll
    for (int ni = 0; ni < 4; ++ni) {
        const int cg = n0 + C0 + ni * 16 + ml;
        const int bix = hz * bstride + cg;
        const float bv = biasv ? (bias32 ? ((const float*)biasv)[bix] : (float)((const bf16*)biasv)[bix]) : 0.f;
        #pragma unroll
        for (int mi = 0; mi < 8; ++mi) {
            const int rg = m0 + R0 + mi * 16 + quad * 4;
            #pragma unroll
            for (int r = 0; r < 4; ++r) {
                const float val = acc[mi][ni][r] * alpha + bv;
                const size_t idx = offC + (size_t)(rg + r) * ldc + cg;
                if (c32) ((float*)Cv)[idx] = val;
                else     ((bf16*)Cv)[idx] = (bf16)val;
            }
        }
    }
}

// In-place row softmax, rows of exactly 512 bf16. One wave per row (8 elems/lane).
__global__ __launch_bounds__(256) void softmax512(bf16* __restrict__ buf)
{
    const int row = blockIdx.x * 4 + (threadIdx.x >> 6);
    const int l = threadIdx.x & 63;
    bf16* p = buf + (size_t)row * 512 + l * 8;
    bf16x8 v = *(const bf16x8*)p;
    float f[8];
    float mx = -1e30f;
    #pragma unroll
    for (int j = 0; j < 8; ++j) {
        f[j] = (float)v[j];
        if (!(fabsf(f[j]) < 1e30f)) f[j] = -1e9f;   // NaN/Inf guard
        mx = fmaxf(mx, f[j]);
    }
    #pragma unroll
    for (int s = 1; s < 64; s <<= 1) mx = fmaxf(mx, __shfl_xor(mx, s));
    float sum = 0.f;
    #pragma unroll
    for (int j = 0; j < 8; ++j) { f[j] = __expf(f[j] - mx); sum += f[j]; }
    #pragma unroll
    for (int s = 1; s < 64; s <<= 1) sum += __shfl_xor(sum, s);
    const float inv = 1.f / sum;
    #pragma unroll
    for (int j = 0; j < 8; ++j) v[j] = (bf16)(f[j] * inv);
    *(bf16x8*)p = v;
}

// Merged per-head transpose: zz<32 -> (in1->out1), else (in2->out2), z=zz&31.
// out[z][d][s] = in[b][s][h*512+d], z = b*8+h. 32x32 tiles via LDS.
__global__ __launch_bounds__(256) void transpose_heads2(
    const bf16* __restrict__ in1, bf16* __restrict__ out1,
    const bf16* __restrict__ in2, bf16* __restrict__ out2)
{
    __shared__ bf16 tile[32][33];
    const int zz = blockIdx.z;
    const bf16* in = (zz < 32) ? in1 : in2;
    bf16* out = (zz < 32) ? out1 : out2;
    const int z = zz & 31, b = z >> 3, h = z & 7;
    const int s0 = blockIdx.x * 32, d0 = blockIdx.y * 32;
    const int tx = threadIdx.x, ty = threadIdx.y;   // 32 x 8
    #pragma unroll
    for (int j = 0; j < 4; ++j) {
        const int s = s0 + ty + j * 8;
        tile[ty + j * 8][tx] = in[(size_t)b * SK_ * DM_ + (size_t)s * DM_ + h * DK_ + d0 + tx];
    }
    __syncthreads();
    #pragma unroll
    for (int j = 0; j < 4; ++j) {
        const int d = d0 + ty + j * 8;
        out[(size_t)z * DK_ * SK_ + (size_t)d * SK_ + s0 + tx] = tile[tx][ty + j * 8];
    }
}

extern "C" void kernel_launch(void* const* d_in, const int* in_sizes, int n_in,
                              void* d_out, int out_size, void* d_ws, size_t ws_size,
                              hipStream_t stream)
{
    const void* query = d_in[0];
    const void* key   = d_in[1];
    const void* value = d_in[2];
    const void* imf   = d_in[3];
    const void* W0 = d_in[4];  const void* b0 = d_in[5];
    const void* W1 = d_in[6];  const void* b1 = d_in[7];
    const void* W2 = d_in[8];  const void* b2 = d_in[9];
    const void* W3 = d_in[10]; const void* b3 = d_in[11];

    // ---- workspace (bf16 elems; >=58.7M proven). Liveness-audited offsets:
    bf16* ws    = (bf16*)d_ws;
    int*  flagp = (int*)d_ws;
    bf16* wS1   = ws + 8;                    // 16.8M: W0 -> W1 -> (vT,imfT) -> W3final
    bf16* wS2   = ws + 16777224;             // 16.8M: W2 -> W3 -> s1/xcat start
    bf16* vT    = ws + 8;                    //  8.4M (W slots dead after KV GEMM)
    bf16* imfT  = ws + 8388616;              //  8.4M
    bf16* w3s   = ws + 16777224;             // 16.8M (dead after imf GEMM)
    bf16* imfp  = ws + 33554440;             //  8.4M (dead after transpose)
    bf16* s1    = ws + 16777224;             // 33.5M (overlays dead w3s+imfp; ends 50.3M)
    bf16* xcat  = ws + 16777224;             // 33.5M (overlays dead s1)
    bf16* w3f   = ws + 8;                    // 16.8M (after vT/imfT die)
    bf16* wbias = ws + 50331656;             // 16K: staged b1|b2 (dtype follows flag)

    // ---- d_out (67.1M bf16 elems), multi-duty until final GEMM fills it ----
    bf16* obase = (bf16*)d_out;
    bf16* qproj = obase;                     // 33.5M (dead after scores GEMM)
    bf16* qbf   = obase + 33554432;          // 33.5M (dead after Q proj)
    bf16* kin   = obase + 33554432;          //  8.4M (k/v contiguous inputs)
    bf16* vin   = obase + 41943040;          //  8.4M
    bf16* iin   = obase + 33554432;          //  8.4M (reuses dead kin)
    bf16* kproj = obase + 50331648;          //  8.4M (kproj/vproj contiguous, sCh=8.4M)
    bf16* vproj = obase + 58720256;          //  8.4M (dead after transpose)
    bf16* s2    = obase + 33554432;          // 33.5M (after iin/vin/kproj/vproj die)

    const float inv_sqrt_dk = 0.04419417382415922f;  // 1/sqrt(512)

    // 0: decide external dtype (fp32 vs bf16) from query's bit patterns
    sniff_dtype<<<1, 64, 0, stream>>>((const uint32_t*)query, flagp);

    // ---- Q path: convert, project (16x32 = 512 WGs = 2 full rounds) ----
    cvt_to_bf16<<<16384, 256, 0, stream>>>(query, qbf, flagp);
    cvt_to_bf16<<<8192, 256, 0, stream>>>(W0, wS1, flagp);
    gemm256<<<dim3(16, 32, 1), 512, 0, stream>>>(qbf, wS1, qproj, b0,
        4096, 4096, 4096, 4096, 1.f, 0,0,0,0,0,0, flagp, 1, 0);

    // ---- K+V batched projection: z=2, grid (16,8,2) = 256 WGs = 1 WG/CU ----
    cvt2_to_bf16<<<8192, 256, 0, stream>>>(key, kin, value, vin, 4096, flagp);
    cvt2_to_bf16<<<16384, 256, 0, stream>>>(W1, wS1, W2, wS2, 8192, flagp);
    copy_bias2<<<32, 256, 0, stream>>>(b1, b2, wbias, flagp);
    gemm256<<<dim3(16, 8, 2), 512, 0, stream>>>(kin, wS1, kproj, wbias,
        4096, 4096, 4096, 4096, 1.f,
        0LL, 8388608LL, 0LL, 16777216LL, 0LL, 8388608LL,
        flagp, 1, 4096);

    // ---- imf projection (gemm_bt: 512 WGs fills better than 128-WG 256^2) ----
    cvt2_to_bf16<<<12288, 256, 0, stream>>>(imf, iin, W3, w3s, 4096, flagp);
    gemm_bt<<<dim3(32, 16, 1), 256, 0, stream>>>(iin, w3s, imfp, b3,
        4096, 4096, 4096, 4096, 1.f, 0,0,0,0,0,0, flagp, 1);

    // ---- both per-head transposes in one launch ----
    transpose_heads2<<<dim3(16, 16, 64), dim3(32, 8), 0, stream>>>(vproj, vT, imfp, imfT);

    // ---- scores = q·k^T / sqrt(dk)  (2x8x32 = 512 WGs) ----
    gemm256<<<dim3(2, 8, 32), 512, 0, stream>>>(qproj, kproj, s1, nullptr,
        512, 4096, 4096, 512, inv_sqrt_dk,
        (long long)SQ_*DM_, (long long)DK_, (long long)SK_*DM_, (long long)DK_,
        (long long)H_*SQ_*SK_, (long long)SQ_*SK_, flagp, 0, 0);
    softmax512<<<dim3(16384), 256, 0, stream>>>(s1);
    // ---- s2 = p @ imf_h ----
    gemm256<<<dim3(2, 8, 32), 512, 0, stream>>>(s1, imfT, s2, nullptr,
        512, 512, 512, 512, 1.f,
        (long long)H_*SQ_*SK_, (long long)SQ_*SK_, (long long)H_*DK_*SK_, (long long)DK_*SK_,
        (long long)H_*SQ_*SK_, (long long)SQ_*SK_, flagp, 0, 0);
    softmax512<<<dim3(16384), 256, 0, stream>>>(s2);
    // ---- x = im_attn @ v_h -> concat-head layout (xcat overlays dead s1) ----
    gemm256<<<dim3(2, 8, 32), 512, 0, stream>>>(s2, vT, xcat, nullptr,
        512, 512, 512, 4096, 1.f,
        (long long)H_*SQ_*SK_, (long long)SQ_*SK_, (long long)H_*DK_*SK_, (long long)DK_*SK_,
        (long long)SQ_*DM_, (long long)DK_, flagp, 0, 0);
    // ---- out = xcat @ W3^T + b3 (re-convert W3 into dead vT/imfT region) ----
    cvt_to_bf16<<<8192, 256, 0, stream>>>(W3, w3f, flagp);
    gemm256<<<dim3(16, 32, 1), 512, 0, stream>>>(xcat, w3f, d_out, b3,
        4096, 4096, 4096, 4096, 1.f, 0,0,0,0,0,0, flagp, 3, 0);
}